// Round 18
// baseline (572.612 us; speedup 1.0000x reference)
//
#include <hip/hip_runtime.h>
#include <hip/hip_fp16.h>
#include <math.h>

#define N_NODES 40000
#define N_EDGES 640000
#define FIN 64
#define HID 128
#define OUTDIM 64
#define HEADS 4
#define NGROUPS 64
#define NCOLS 512   // HEADS*HID

typedef _Float16 half8 __attribute__((ext_vector_type(8)));
typedef float f32x4 __attribute__((ext_vector_type(4)));

__device__ __forceinline__ float lrelu(float x) { return x > 0.f ? x : 0.2f * x; }

// ---- fused prep: x->fp16 | Wbig fragment-major swizzle (3 layers) | vtab ----
// Wbig_l[(h*K+k)][c] = 0.25 * W_l[k][h*128+c]  (head-mean folded in), fragment-major
#define PREP_X4   (N_NODES * FIN / 4)                 // 640000
#define PREP_WSWZ 20480                               // 4096 + 8192 + 8192
#define PREP_V    2560                                // (FIN + 2*HID) * 8
__global__ void prep_kernel(const float* __restrict__ x, __half* __restrict__ x16,
                            const float* __restrict__ W0, const float* __restrict__ W1,
                            const float* __restrict__ W2,
                            _Float16* __restrict__ F0, _Float16* __restrict__ F1,
                            _Float16* __restrict__ F2,
                            const float* __restrict__ as0, const float* __restrict__ ad0,
                            const float* __restrict__ as1, const float* __restrict__ ad1,
                            const float* __restrict__ as2, const float* __restrict__ ad2,
                            float* __restrict__ v0, float* __restrict__ v1,
                            float* __restrict__ v2) {
    int id = blockIdx.x * 256 + threadIdx.x;
    if (id < PREP_X4) {
        int i4 = id * 4;
        float4 v = *(const float4*)(x + i4);
        __half2 a = __floats2half2_rn(v.x, v.y);
        __half2 b = __floats2half2_rn(v.z, v.w);
        *(__half2*)(x16 + i4)     = a;
        *(__half2*)(x16 + i4 + 2) = b;
        return;
    }
    id -= PREP_X4;
    if (id < PREP_WSWZ) {
        const float* W; _Float16* F; int Kin;
        if (id < 4096)       { W = W0; F = F0; Kin = FIN; }
        else if (id < 12288) { W = W1; F = F1; Kin = HID; id -= 4096; }
        else                 { W = W2; F = F2; Kin = HID; id -= 12288; }
        int KP = Kin * 4;
        int NKg = KP / 32;
        int lane = id & 63;
        int blob = id >> 6;
        int k0g = blob % NKg;
        int cb  = blob / NKg;
        int col = cb * 16 + (lane & 15);
        int kkb = k0g * 32 + (lane >> 4) * 8;
        half8 v;
        #pragma unroll
        for (int e = 0; e < 8; ++e) {
            int kk = kkb + e;
            int k = kk & (Kin - 1);
            int h = kk / Kin;
            v[e] = (_Float16)(0.25f * W[(size_t)k * NCOLS + h * HID + col]);
        }
        *(half8*)(F + (size_t)blob * 512 + lane * 8) = v;
        return;
    }
    id -= PREP_WSWZ;
    if (id < PREP_V) {
        const float* W; const float* as_; const float* ad_; float* v; int j = id;
        if (j < FIN * 8)              { W = W0; as_ = as0; ad_ = ad0; v = v0; }
        else if (j < (FIN + HID) * 8) { W = W1; as_ = as1; ad_ = ad1; v = v1; j -= FIN * 8; }
        else                          { W = W2; as_ = as2; ad_ = ad2; v = v2; j -= (FIN + HID) * 8; }
        int k = j >> 3, sd = (j >> 2) & 1, h = j & 3;
        const float* av = sd ? ad_ : as_;
        float acc = 0.f;
        for (int c = 0; c < HID; ++c)
            acc += W[(size_t)k * NCOLS + h * HID + c] * av[h * HID + c];
        v[k * 8 + sd * 4 + h] = acc;
    }
}

// ---------------- CSR build ----------------
__global__ void deg_count_kernel(const int* __restrict__ ei, int* deg) {
    int e = blockIdx.x * blockDim.x + threadIdx.x;
    if (e < N_EDGES) atomicAdd(&deg[ei[N_EDGES + e]], 1);
}

__global__ void scan1_kernel(const int* __restrict__ deg, int* offsets, int* partial) {
    __shared__ int buf[256];
    int t = threadIdx.x;
    int i = blockIdx.x * 256 + t;
    int v = (i < N_NODES) ? deg[i] + 1 : 0;   // +1 = self loop
    buf[t] = v;
    __syncthreads();
    for (int off = 1; off < 256; off <<= 1) {
        int y = (t >= off) ? buf[t - off] : 0;
        __syncthreads();
        buf[t] += y;
        __syncthreads();
    }
    if (i < N_NODES) offsets[i] = buf[t] - v;
    if (t == 255) partial[blockIdx.x] = buf[255];
}

__global__ void scan2_kernel(int* partial, int nb) {
    __shared__ int buf[256];
    int t = threadIdx.x;
    int v = (t < nb) ? partial[t] : 0;
    buf[t] = v;
    __syncthreads();
    for (int off = 1; off < 256; off <<= 1) {
        int y = (t >= off) ? buf[t - off] : 0;
        __syncthreads();
        buf[t] += y;
        __syncthreads();
    }
    if (t < nb) partial[t] = buf[t] - v;
}

__global__ void scan3_kernel(int* offsets, int* pos, const int* __restrict__ partial) {
    int i = blockIdx.x * 256 + threadIdx.x;
    if (i < N_NODES) {
        int o = offsets[i] + partial[i >> 8];
        offsets[i] = o;
        pos[i] = o;
    }
    if (i == 0) offsets[N_NODES] = N_EDGES + N_NODES;
}

__global__ void scatter_kernel(const int* __restrict__ ei, int* pos, int* csr_src) {
    int i = blockIdx.x * blockDim.x + threadIdx.x;
    if (i < N_EDGES) {
        int s = ei[i];
        int d = ei[N_EDGES + i];
        csr_src[atomicAdd(&pos[d], 1)] = s;
    } else if (i < N_EDGES + N_NODES) {
        int nn = i - N_EDGES;
        csr_src[atomicAdd(&pos[nn], 1)] = nn;
    }
}

// ------- scores for layer 0: one THREAD per node, vtab in LDS ---------
template <int K>
__global__ __launch_bounds__(256) void scores3_kernel(const __half* __restrict__ x,
                                                      const float* __restrict__ v,
                                                      float* __restrict__ ssrc,
                                                      float* __restrict__ sdst) {
    __shared__ float vs[K * 8];
    int t = threadIdx.x;
    for (int i = t; i < K * 8; i += 256) vs[i] = v[i];
    __syncthreads();
    int node = blockIdx.x * 256 + t;
    if (node >= N_NODES) return;
    const __half* xr = x + (size_t)node * K;
    f32x4 as = {0.f, 0.f, 0.f, 0.f};
    f32x4 ad = {0.f, 0.f, 0.f, 0.f};
    #pragma unroll 4
    for (int k0 = 0; k0 < K; k0 += 8) {
        uint4 u = *(const uint4*)(xr + k0);
        __half2* hp = (__half2*)&u;
        #pragma unroll
        for (int q = 0; q < 4; ++q) {
            float2 f = __half22float2(hp[q]);
            int k = k0 + 2 * q;
            as += f.x * *(const f32x4*)&vs[k * 8];
            ad += f.x * *(const f32x4*)&vs[k * 8 + 4];
            as += f.y * *(const f32x4*)&vs[(k + 1) * 8];
            ad += f.y * *(const f32x4*)&vs[(k + 1) * 8 + 4];
        }
    }
    *(f32x4*)(ssrc + node * 4) = as;
    *(f32x4*)(sdst + node * 4) = ad;
}

// ---- FUSED layer v5: inline softmax numerators + deferred normalization ----
// val_j = exp(lrelu(ssrc[src_j] + sdst[n])) computed in-loop (ssrc: 640KB
// L2-resident 16B gathers; bitwise-identical to the old edge_val pass).
// acc = (sum val_j x_j) * (1/sum val_j); dsum rides the existing reduce tree.
// LDS: tb aliases As. launch_bounds(512,8) pins VGPR<=64 (8 waves/SIMD).
template <int K, bool SCORES>
__global__ __launch_bounds__(512, 8) void fused_layer_kernel(
        const __half* __restrict__ tab16,
        const float* __restrict__ s_src,
        const float* __restrict__ s_dst,
        const int* __restrict__ offsets,
        const int* __restrict__ csr_src,
        const _Float16* __restrict__ Wf,
        const float* __restrict__ bias,
        const float* __restrict__ gamma,
        const float* __restrict__ beta,
        const float* __restrict__ vtab_next,
        __half* __restrict__ h16out,
        float* __restrict__ ssrc_o,
        float* __restrict__ sdst_o) {
    constexpr int KP = 4 * K;
    constexpr int EPR = (K == 128) ? 4 : 8;   // edges per gather round
    constexpr int LPE = 64 / EPR;             // lanes per edge
    constexpr int NKg = KP / 32;

    __shared__ _Float16 As[32][KP + 8];
    __shared__ float bn_s[3][HID];
    __shared__ float vs[SCORES ? HID * 8 : 8];
    _Float16 (*tb)[136] = (_Float16(*)[136])&As[0][0];   // aliases As (phase-2 only)

    int t = threadIdx.x;
    int lane = t & 63;
    int wv = t >> 6;          // 0..7
    int bm = blockIdx.x * 32;

    if (t < HID) {
        bn_s[0][t] = bias[t];
        bn_s[1][t] = gamma[t] * rsqrtf(1.f + 1e-5f);
        bn_s[2][t] = beta[t];
    }
    if (SCORES)
        for (int i = t; i < HID * 8; i += 512) vs[i] = vtab_next[i];

    int cgrp = lane & (LPE - 1);
    int egoff = lane / LPE;
    const char* xb = (const char*)tab16 + cgrp * 16;

    // -------- phase 1: gather 4 nodes per wave, 2 rounds in flight --------
    for (int i = 0; i < 4; ++i) {
        int nl = wv * 4 + i;
        int n = bm + nl;
        int start = offsets[n], end = offsets[n + 1];
        int deg = end - start;
        const float4 sd = *(const float4*)(s_dst + n * 4);
        float acc[4][8] = {};
        f32x4 dsum = {0.f, 0.f, 0.f, 0.f};

        int j = 0;
        for (; j + 2 * EPR <= deg; j += 2 * EPR) {
            // both rounds fully in-range -> no masks
            int egA = start + j + egoff;
            int egB = egA + EPR;
            int srcA = csr_src[egA];
            int srcB = csr_src[egB];
            float4 qA = *(const float4*)(s_src + srcA * 4);
            float4 qB = *(const float4*)(s_src + srcB * 4);
            uint4 uA = *(const uint4*)(xb + (uint)srcA * (K * 2));
            uint4 uB = *(const uint4*)(xb + (uint)srcB * (K * 2));
            f32x4 aA, aB;
            aA[0] = __expf(lrelu(qA.x + sd.x));
            aA[1] = __expf(lrelu(qA.y + sd.y));
            aA[2] = __expf(lrelu(qA.z + sd.z));
            aA[3] = __expf(lrelu(qA.w + sd.w));
            aB[0] = __expf(lrelu(qB.x + sd.x));
            aB[1] = __expf(lrelu(qB.y + sd.y));
            aB[2] = __expf(lrelu(qB.z + sd.z));
            aB[3] = __expf(lrelu(qB.w + sd.w));
            dsum += aA;
            dsum += aB;
            __half2* hA = (__half2*)&uA;
            __half2* hB = (__half2*)&uB;
            #pragma unroll
            for (int q = 0; q < 4; ++q) {
                float2 fA = __half22float2(hA[q]);
                float2 fB = __half22float2(hB[q]);
                #pragma unroll
                for (int h = 0; h < 4; ++h) {
                    acc[h][2 * q]     += aA[h] * fA.x + aB[h] * fB.x;
                    acc[h][2 * q + 1] += aA[h] * fA.y + aB[h] * fB.y;
                }
            }
        }
        for (; j < deg; j += EPR) {
            int eg = j + egoff;
            bool act = eg < deg;
            int ec = act ? eg : deg - 1;
            int src = csr_src[start + ec];
            float4 qq = *(const float4*)(s_src + src * 4);
            f32x4 a4;
            a4[0] = act ? __expf(lrelu(qq.x + sd.x)) : 0.f;
            a4[1] = act ? __expf(lrelu(qq.y + sd.y)) : 0.f;
            a4[2] = act ? __expf(lrelu(qq.z + sd.z)) : 0.f;
            a4[3] = act ? __expf(lrelu(qq.w + sd.w)) : 0.f;
            dsum += a4;
            uint4 u = *(const uint4*)(xb + (uint)src * (K * 2));
            __half2* hp = (__half2*)&u;
            #pragma unroll
            for (int q = 0; q < 4; ++q) {
                float2 f = __half22float2(hp[q]);
                #pragma unroll
                for (int h = 0; h < 4; ++h) {
                    acc[h][2 * q]     += a4[h] * f.x;
                    acc[h][2 * q + 1] += a4[h] * f.y;
                }
            }
        }

        // reduce across edge groups (lanes sharing cgrp); dsum rides along
        #pragma unroll
        for (int stride = LPE; stride < 64; stride <<= 1) {
            #pragma unroll
            for (int h = 0; h < 4; ++h) {
                #pragma unroll
                for (int r = 0; r < 8; ++r)
                    acc[h][r] += __shfl_xor(acc[h][r], stride);
                dsum[h] += __shfl_xor(dsum[h], stride);
            }
        }
        if (lane < LPE) {
            #pragma unroll
            for (int h = 0; h < 4; ++h) {
                float inv = 1.f / dsum[h];
                half8 v;
                #pragma unroll
                for (int r = 0; r < 8; ++r) v[r] = (_Float16)(acc[h][r] * inv);
                *(half8*)&As[nl][h * K + cgrp * 8] = v;
            }
        }
    }
    __syncthreads();

    // -------- phase 2: MFMA epilogue GEMM [32,KP]@[KP,128] --------
    int wm = wv >> 2, wn = wv & 3;
    int lr = lane & 15;
    int lk = (lane >> 4) * 8;
    int lg = lane >> 4;
    f32x4 acc2[2] = {};
    #pragma unroll
    for (int k0g = 0; k0g < NKg; ++k0g) {
        half8 af = *(const half8*)&As[wm * 16 + lr][k0g * 32 + lk];
        #pragma unroll
        for (int nn = 0; nn < 2; ++nn) {
            int cb = wn * 2 + nn;
            half8 bf = *(const half8*)(Wf + ((size_t)(cb * NKg + k0g) << 9) + lane * 8);
            acc2[nn] = __builtin_amdgcn_mfma_f32_16x16x32_f16(af, bf, acc2[nn], 0, 0, 0);
        }
    }
    __syncthreads();   // As fully consumed; tb may now overwrite it

    // epilogue: bias + BN + ReLU -> tb (aliases As)
    #pragma unroll
    for (int nn = 0; nn < 2; ++nn) {
        int col = wn * 32 + nn * 16 + lr;
        float b = bn_s[0][col], g = bn_s[1][col], be = bn_s[2][col];
        #pragma unroll
        for (int r = 0; r < 4; ++r) {
            float o = acc2[nn][r] + b;
            o = o * g + be;
            tb[wm * 16 + lg * 4 + r][col] = (_Float16)fmaxf(o, 0.f);
        }
    }
    __syncthreads();

    // coalesced h16 write: 32 rows x 128 cols
    {
        int row = t >> 4;
        int c0 = (t & 15) * 8;
        half8 v0 = *(const half8*)&tb[row][c0];
        *(half8*)((_Float16*)h16out + (size_t)(bm + row) * HID + c0) = v0;
    }

    // fused next-layer scores from output tile
    if (SCORES) {
        if (t < 256) {
            int node = t >> 3, j = t & 7;
            float sacc = 0.f;
            #pragma unroll 2
            for (int k0 = 0; k0 < HID; k0 += 8) {
                half8 hv = *(const half8*)&tb[node][k0];
                #pragma unroll
                for (int e = 0; e < 8; ++e)
                    sacc += (float)hv[e] * vs[(k0 + e) * 8 + j];
            }
            if (j < 4) ssrc_o[(bm + node) * 4 + j] = sacc;
            else       sdst_o[(bm + node) * 4 + (j - 4)] = sacc;
        }
    }
}

// ------- pooling: 2 nodes in flight, uint (2-channel) loads ----------------
__global__ __launch_bounds__(128) void pool_kernel(const __half* __restrict__ h,
                                                   const int* __restrict__ batch,
                                                   float* pooled, float* counts) {
    int t = threadIdx.x;
    int which = t >> 6;
    int c2 = (t & 63) * 2;
    int n0 = blockIdx.x * 256 + which;
    int n1 = min(blockIdx.x * 256 + 256, N_NODES);
    if (n0 >= N_NODES) return;
    int cg = batch[n0];
    float a0 = 0.f, a1 = 0.f, cnt = 0.f;
    for (int n = n0; n < n1; n += 2) {
        int g = batch[n];
        if (g != cg) {
            atomicAdd(&pooled[cg * HID + c2], a0);
            atomicAdd(&pooled[cg * HID + c2 + 1], a1);
            if ((t & 63) == 0) atomicAdd(&counts[cg], cnt);
            a0 = 0.f; a1 = 0.f; cnt = 0.f; cg = g;
        }
        uint u = *(const uint*)(h + (size_t)n * HID + c2);
        __half2 hh = *(__half2*)&u;
        float2 f = __half22float2(hh);
        a0 += f.x; a1 += f.y; cnt += 1.f;
    }
    atomicAdd(&pooled[cg * HID + c2], a0);
    atomicAdd(&pooled[cg * HID + c2 + 1], a1);
    if ((t & 63) == 0) atomicAdd(&counts[cg], cnt);
}

// ---------------- head: mean-divide + fc1 + relu + fc2 ----------------
__global__ __launch_bounds__(128) void head_kernel(const float* __restrict__ pooled,
                                                   const float* __restrict__ counts,
                                                   const float* __restrict__ fc1_w,
                                                   const float* __restrict__ fc1_b,
                                                   const float* __restrict__ fc2_w,
                                                   const float* __restrict__ fc2_b,
                                                   float* __restrict__ out) {
    int gI = blockIdx.x;
    int t = threadIdx.x;
    __shared__ float p[HID], hb[HID];
    p[t] = pooled[gI * HID + t] / fmaxf(counts[gI], 1.f);
    __syncthreads();
    float a = fc1_b[t];
    #pragma unroll 4
    for (int k = 0; k < HID; ++k) a += p[k] * fc1_w[k * HID + t];
    hb[t] = fmaxf(a, 0.f);
    __syncthreads();
    if (t < OUTDIM) {
        float o = fc2_b[t];
        #pragma unroll 4
        for (int k = 0; k < HID; ++k) o += hb[k] * fc2_w[k * OUTDIM + t];
        out[gI * OUTDIM + t] = o;
    }
}

extern "C" void kernel_launch(void* const* d_in, const int* in_sizes, int n_in,
                              void* d_out, int out_size, void* d_ws, size_t ws_size,
                              hipStream_t stream) {
    const float* x     = (const float*)d_in[0];
    const int*   ei    = (const int*)d_in[1];
    const int*   batch = (const int*)d_in[2];
    const float* W[3]  = {(const float*)d_in[3],  (const float*)d_in[9],  (const float*)d_in[15]};
    const float* As_[3] = {(const float*)d_in[4],  (const float*)d_in[10], (const float*)d_in[16]};
    const float* Ad[3] = {(const float*)d_in[5],  (const float*)d_in[11], (const float*)d_in[17]};
    const float* Bb[3] = {(const float*)d_in[6],  (const float*)d_in[12], (const float*)d_in[18]};
    const float* Gg[3] = {(const float*)d_in[7],  (const float*)d_in[13], (const float*)d_in[19]};
    const float* Be[3] = {(const float*)d_in[8],  (const float*)d_in[14], (const float*)d_in[20]};
    const float* fc1_w = (const float*)d_in[21];
    const float* fc1_b = (const float*)d_in[22];
    const float* fc2_w = (const float*)d_in[23];
    const float* fc2_b = (const float*)d_in[24];

    char* ws = (char*)d_ws;
    size_t off = 0;
    auto alloc = [&](size_t bytes) {
        void* p = ws + off;
        off = (off + bytes + 255) & ~(size_t)255;
        return p;
    };
    __half* x16    = (__half*)alloc((size_t)N_NODES * FIN * 2);
    __half* h16A   = (__half*)alloc((size_t)N_NODES * HID * 2);
    __half* h16B   = (__half*)alloc((size_t)N_NODES * HID * 2);
    _Float16* Wf[3];
    Wf[0] = (_Float16*)alloc((size_t)(4 * FIN) * HID * 2);
    Wf[1] = (_Float16*)alloc((size_t)(4 * HID) * HID * 2);
    Wf[2] = (_Float16*)alloc((size_t)(4 * HID) * HID * 2);
    float* vtab[3];
    vtab[0] = (float*)alloc((size_t)FIN * 8 * 4);
    vtab[1] = (float*)alloc((size_t)HID * 8 * 4);
    vtab[2] = (float*)alloc((size_t)HID * 8 * 4);
    float* ssrcA   = (float*)alloc((size_t)N_NODES * HEADS * 4);
    float* sdstA   = (float*)alloc((size_t)N_NODES * HEADS * 4);
    float* ssrcB   = (float*)alloc((size_t)N_NODES * HEADS * 4);
    float* sdstB   = (float*)alloc((size_t)N_NODES * HEADS * 4);
    int*   deg     = (int*)alloc((size_t)N_NODES * 4);
    int*   offsets = (int*)alloc((size_t)(N_NODES + 1) * 4);
    int*   pos     = (int*)alloc((size_t)N_NODES * 4);
    int*   partial = (int*)alloc((size_t)256 * 4);
    int*   csr     = (int*)alloc((size_t)(N_EDGES + N_NODES) * 4);
    float* pooled  = (float*)alloc((size_t)NGROUPS * HID * 4 + (size_t)NGROUPS * 4);
    float* counts  = pooled + (size_t)NGROUPS * HID;

    // fused prep: x16 + fragment-major Wbig + vtab
    const int PREP_TOTAL = PREP_X4 + PREP_WSWZ + PREP_V;
    prep_kernel<<<(PREP_TOTAL + 255) / 256, 256, 0, stream>>>(
        x, x16, W[0], W[1], W[2], Wf[0], Wf[1], Wf[2],
        As_[0], Ad[0], As_[1], Ad[1], As_[2], Ad[2], vtab[0], vtab[1], vtab[2]);

    // CSR by dst (with self loops)
    const int NB = (N_NODES + 255) / 256;   // 157
    hipMemsetAsync(deg, 0, (size_t)N_NODES * 4, stream);
    deg_count_kernel<<<(N_EDGES + 255) / 256, 256, 0, stream>>>(ei, deg);
    scan1_kernel<<<NB, 256, 0, stream>>>(deg, offsets, partial);
    scan2_kernel<<<1, 256, 0, stream>>>(partial, NB);
    scan3_kernel<<<NB, 256, 0, stream>>>(offsets, pos, partial);
    scatter_kernel<<<(N_EDGES + N_NODES + 255) / 256, 256, 0, stream>>>(ei, pos, csr);

    // layer-0 scores from x16 -> A
    scores3_kernel<64><<<NB, 256, 0, stream>>>(x16, vtab[0], ssrcA, sdstA);

    // layer 0: in x16 + scores A -> out h16A, scores B
    fused_layer_kernel<64, true><<<N_NODES / 32, 512, 0, stream>>>(
        x16, ssrcA, sdstA, offsets, csr, Wf[0], Bb[0], Gg[0], Be[0],
        vtab[1], h16A, ssrcB, sdstB);
    // layer 1: in h16A + scores B -> out h16B, scores A
    fused_layer_kernel<128, true><<<N_NODES / 32, 512, 0, stream>>>(
        h16A, ssrcB, sdstB, offsets, csr, Wf[1], Bb[1], Gg[1], Be[1],
        vtab[2], h16B, ssrcA, sdstA);
    // layer 2: in h16B + scores A -> out h16A, no score write
    fused_layer_kernel<128, false><<<N_NODES / 32, 512, 0, stream>>>(
        h16B, ssrcA, sdstA, offsets, csr, Wf[2], Bb[2], Gg[2], Be[2],
        nullptr, h16A, nullptr, nullptr);

    // global mean pool + MLP head
    hipMemsetAsync(pooled, 0, (size_t)NGROUPS * HID * 4 + (size_t)NGROUPS * 4, stream);
    pool_kernel<<<(N_NODES + 255) / 256, 128, 0, stream>>>(h16A, batch, pooled, counts);
    head_kernel<<<NGROUPS, 128, 0, stream>>>(pooled, counts, fc1_w, fc1_b, fc2_w, fc2_b,
                                             (float*)d_out);
}

// Round 19
// 370.061 us; speedup vs baseline: 1.5473x; 1.5473x over previous
//
#include <hip/hip_runtime.h>
#include <hip/hip_fp16.h>
#include <math.h>

#define N_NODES 40000
#define N_EDGES 640000
#define FIN 64
#define HID 128
#define OUTDIM 64
#define HEADS 4
#define NGROUPS 64
#define NCOLS 512   // HEADS*HID

typedef _Float16 half8 __attribute__((ext_vector_type(8)));
typedef float f32x4 __attribute__((ext_vector_type(4)));

__device__ __forceinline__ float lrelu(float x) { return x > 0.f ? x : 0.2f * x; }

// ---- fused prep: x->fp16 | Wbig fragment-major swizzle (3 layers) | vtab ----
// Wbig_l[(h*K+k)][c] = 0.25 * W_l[k][h*128+c]  (head-mean folded in), fragment-major
#define PREP_X4   (N_NODES * FIN / 4)                 // 640000
#define PREP_WSWZ 20480                               // 4096 + 8192 + 8192
#define PREP_V    2560                                // (FIN + 2*HID) * 8
__global__ void prep_kernel(const float* __restrict__ x, __half* __restrict__ x16,
                            const float* __restrict__ W0, const float* __restrict__ W1,
                            const float* __restrict__ W2,
                            _Float16* __restrict__ F0, _Float16* __restrict__ F1,
                            _Float16* __restrict__ F2,
                            const float* __restrict__ as0, const float* __restrict__ ad0,
                            const float* __restrict__ as1, const float* __restrict__ ad1,
                            const float* __restrict__ as2, const float* __restrict__ ad2,
                            float* __restrict__ v0, float* __restrict__ v1,
                            float* __restrict__ v2) {
    int id = blockIdx.x * 256 + threadIdx.x;
    if (id < PREP_X4) {
        int i4 = id * 4;
        float4 v = *(const float4*)(x + i4);
        __half2 a = __floats2half2_rn(v.x, v.y);
        __half2 b = __floats2half2_rn(v.z, v.w);
        *(__half2*)(x16 + i4)     = a;
        *(__half2*)(x16 + i4 + 2) = b;
        return;
    }
    id -= PREP_X4;
    if (id < PREP_WSWZ) {
        const float* W; _Float16* F; int Kin;
        if (id < 4096)       { W = W0; F = F0; Kin = FIN; }
        else if (id < 12288) { W = W1; F = F1; Kin = HID; id -= 4096; }
        else                 { W = W2; F = F2; Kin = HID; id -= 12288; }
        int KP = Kin * 4;
        int NKg = KP / 32;
        int lane = id & 63;
        int blob = id >> 6;
        int k0g = blob % NKg;
        int cb  = blob / NKg;
        int col = cb * 16 + (lane & 15);
        int kkb = k0g * 32 + (lane >> 4) * 8;
        half8 v;
        #pragma unroll
        for (int e = 0; e < 8; ++e) {
            int kk = kkb + e;
            int k = kk & (Kin - 1);
            int h = kk / Kin;
            v[e] = (_Float16)(0.25f * W[(size_t)k * NCOLS + h * HID + col]);
        }
        *(half8*)(F + (size_t)blob * 512 + lane * 8) = v;
        return;
    }
    id -= PREP_WSWZ;
    if (id < PREP_V) {
        const float* W; const float* as_; const float* ad_; float* v; int j = id;
        if (j < FIN * 8)              { W = W0; as_ = as0; ad_ = ad0; v = v0; }
        else if (j < (FIN + HID) * 8) { W = W1; as_ = as1; ad_ = ad1; v = v1; j -= FIN * 8; }
        else                          { W = W2; as_ = as2; ad_ = ad2; v = v2; j -= (FIN + HID) * 8; }
        int k = j >> 3, sd = (j >> 2) & 1, h = j & 3;
        const float* av = sd ? ad_ : as_;
        float acc = 0.f;
        for (int c = 0; c < HID; ++c)
            acc += W[(size_t)k * NCOLS + h * HID + c] * av[h * HID + c];
        v[k * 8 + sd * 4 + h] = acc;
    }
}

// ---------------- CSR build ----------------
__global__ void deg_count_kernel(const int* __restrict__ ei, int* deg) {
    int e = blockIdx.x * blockDim.x + threadIdx.x;
    if (e < N_EDGES) atomicAdd(&deg[ei[N_EDGES + e]], 1);
}

__global__ void scan1_kernel(const int* __restrict__ deg, int* offsets, int* partial) {
    __shared__ int buf[256];
    int t = threadIdx.x;
    int i = blockIdx.x * 256 + t;
    int v = (i < N_NODES) ? deg[i] + 1 : 0;   // +1 = self loop
    buf[t] = v;
    __syncthreads();
    for (int off = 1; off < 256; off <<= 1) {
        int y = (t >= off) ? buf[t - off] : 0;
        __syncthreads();
        buf[t] += y;
        __syncthreads();
    }
    if (i < N_NODES) offsets[i] = buf[t] - v;
    if (t == 255) partial[blockIdx.x] = buf[255];
}

__global__ void scan2_kernel(int* partial, int nb) {
    __shared__ int buf[256];
    int t = threadIdx.x;
    int v = (t < nb) ? partial[t] : 0;
    buf[t] = v;
    __syncthreads();
    for (int off = 1; off < 256; off <<= 1) {
        int y = (t >= off) ? buf[t - off] : 0;
        __syncthreads();
        buf[t] += y;
        __syncthreads();
    }
    if (t < nb) partial[t] = buf[t] - v;
}

__global__ void scan3_kernel(int* offsets, int* pos, const int* __restrict__ partial) {
    int i = blockIdx.x * 256 + threadIdx.x;
    if (i < N_NODES) {
        int o = offsets[i] + partial[i >> 8];
        offsets[i] = o;
        pos[i] = o;
    }
    if (i == 0) offsets[N_NODES] = N_EDGES + N_NODES;
}

__global__ void scatter_kernel(const int* __restrict__ ei, int* pos,
                               int* csr_src, int* csr_dst) {
    int i = blockIdx.x * blockDim.x + threadIdx.x;
    if (i < N_EDGES) {
        int s = ei[i];
        int d = ei[N_EDGES + i];
        int p = atomicAdd(&pos[d], 1);
        csr_src[p] = s;
        csr_dst[p] = d;
    } else if (i < N_EDGES + N_NODES) {
        int nn = i - N_EDGES;
        int p = atomicAdd(&pos[nn], 1);
        csr_src[p] = nn;
        csr_dst[p] = nn;
    }
}

// ------- scores for layer 0: one THREAD per node, vtab in LDS ---------
template <int K>
__global__ __launch_bounds__(256) void scores3_kernel(const __half* __restrict__ x,
                                                      const float* __restrict__ v,
                                                      float* __restrict__ ssrc,
                                                      float* __restrict__ sdst) {
    __shared__ float vs[K * 8];
    int t = threadIdx.x;
    for (int i = t; i < K * 8; i += 256) vs[i] = v[i];
    __syncthreads();
    int node = blockIdx.x * 256 + t;
    if (node >= N_NODES) return;
    const __half* xr = x + (size_t)node * K;
    f32x4 as = {0.f, 0.f, 0.f, 0.f};
    f32x4 ad = {0.f, 0.f, 0.f, 0.f};
    #pragma unroll 4
    for (int k0 = 0; k0 < K; k0 += 8) {
        uint4 u = *(const uint4*)(xr + k0);
        __half2* hp = (__half2*)&u;
        #pragma unroll
        for (int q = 0; q < 4; ++q) {
            float2 f = __half22float2(hp[q]);
            int k = k0 + 2 * q;
            as += f.x * *(const f32x4*)&vs[k * 8];
            ad += f.x * *(const f32x4*)&vs[k * 8 + 4];
            as += f.y * *(const f32x4*)&vs[(k + 1) * 8];
            ad += f.y * *(const f32x4*)&vs[(k + 1) * 8 + 4];
        }
    }
    *(f32x4*)(ssrc + node * 4) = as;
    *(f32x4*)(sdst + node * 4) = ad;
}

// ------- edge-parallel softmax numerators, NO atomics -------
__global__ __launch_bounds__(256) void edge_val_kernel(const float* __restrict__ ssrc,
                                                       const float* __restrict__ sdst,
                                                       const int* __restrict__ csr_src,
                                                       const int* __restrict__ csr_dst,
                                                       float* __restrict__ val) {
    int j = blockIdx.x * 256 + threadIdx.x;
    if (j >= N_EDGES + N_NODES) return;
    int s = csr_src[j], d = csr_dst[j];
    float4 a = *(const float4*)(ssrc + s * 4);
    float4 b = *(const float4*)(sdst + d * 4);
    float4 v;
    v.x = __expf(lrelu(a.x + b.x));
    v.y = __expf(lrelu(a.y + b.y));
    v.z = __expf(lrelu(a.z + b.z));
    v.w = __expf(lrelu(a.w + b.w));
    *(float4*)(val + (size_t)j * 4) = v;
}

// ---- FUSED layer v4: deferred-norm gather (2x unrolled) -> LDS As -> MFMA ----
// LDS: tb aliases As (dead after MFMA loop; barrier guards the reuse) -> 38.8KB
// for K=128 => 4 blocks/CU. Hot gather loop: two independent 1KB wave-gathers
// per iteration (no masking), masked single-round tail.
template <int K, bool SCORES>
__global__ __launch_bounds__(512) void fused_layer_kernel(
        const __half* __restrict__ tab16,
        const float* __restrict__ val,
        const int* __restrict__ offsets,
        const int* __restrict__ csr_src,
        const _Float16* __restrict__ Wf,
        const float* __restrict__ bias,
        const float* __restrict__ gamma,
        const float* __restrict__ beta,
        const float* __restrict__ vtab_next,
        __half* __restrict__ h16out,
        float* __restrict__ ssrc_o,
        float* __restrict__ sdst_o) {
    constexpr int KP = 4 * K;
    constexpr int EPR = (K == 128) ? 4 : 8;   // edges per gather round
    constexpr int LPE = 64 / EPR;             // lanes per edge
    constexpr int NKg = KP / 32;

    __shared__ _Float16 As[32][KP + 8];
    __shared__ float bn_s[3][HID];
    __shared__ float vs[SCORES ? HID * 8 : 8];
    _Float16 (*tb)[136] = (_Float16(*)[136])&As[0][0];   // aliases As (phase-2 only)

    int t = threadIdx.x;
    int lane = t & 63;
    int wv = t >> 6;          // 0..7
    int bm = blockIdx.x * 32;

    if (t < HID) {
        bn_s[0][t] = bias[t];
        bn_s[1][t] = gamma[t] * rsqrtf(1.f + 1e-5f);
        bn_s[2][t] = beta[t];
    }
    if (SCORES)
        for (int i = t; i < HID * 8; i += 512) vs[i] = vtab_next[i];

    int cgrp = lane & (LPE - 1);
    int egoff = lane / LPE;
    const char* xb = (const char*)tab16 + cgrp * 16;

    // -------- phase 1: gather 4 nodes per wave, 2 rounds in flight --------
    for (int i = 0; i < 4; ++i) {
        int nl = wv * 4 + i;
        int n = bm + nl;
        int start = offsets[n], end = offsets[n + 1];
        int deg = end - start;
        float acc[4][8] = {};
        f32x4 dsum = {0.f, 0.f, 0.f, 0.f};

        int j = 0;
        for (; j + 2 * EPR <= deg; j += 2 * EPR) {
            // both rounds fully in-range -> no masks
            int egA = start + j + egoff;
            int egB = egA + EPR;
            int srcA = csr_src[egA];
            int srcB = csr_src[egB];
            float4 vA = *(const float4*)(val + (size_t)egA * 4);
            float4 vB = *(const float4*)(val + (size_t)egB * 4);
            uint4 uA = *(const uint4*)(xb + (uint)srcA * (K * 2));
            uint4 uB = *(const uint4*)(xb + (uint)srcB * (K * 2));
            f32x4 aA = {vA.x, vA.y, vA.z, vA.w};
            f32x4 aB = {vB.x, vB.y, vB.z, vB.w};
            dsum += aA;
            dsum += aB;
            __half2* hA = (__half2*)&uA;
            __half2* hB = (__half2*)&uB;
            #pragma unroll
            for (int q = 0; q < 4; ++q) {
                float2 fA = __half22float2(hA[q]);
                float2 fB = __half22float2(hB[q]);
                #pragma unroll
                for (int h = 0; h < 4; ++h) {
                    acc[h][2 * q]     += aA[h] * fA.x + aB[h] * fB.x;
                    acc[h][2 * q + 1] += aA[h] * fA.y + aB[h] * fB.y;
                }
            }
        }
        for (; j < deg; j += EPR) {
            int eg = j + egoff;
            bool act = eg < deg;
            int ec = act ? eg : deg - 1;
            int src = csr_src[start + ec];
            float4 vv = *(const float4*)(val + (size_t)(start + ec) * 4);
            f32x4 a4;
            a4[0] = act ? vv.x : 0.f;
            a4[1] = act ? vv.y : 0.f;
            a4[2] = act ? vv.z : 0.f;
            a4[3] = act ? vv.w : 0.f;
            dsum += a4;
            uint4 u = *(const uint4*)(xb + (uint)src * (K * 2));
            __half2* hp = (__half2*)&u;
            #pragma unroll
            for (int q = 0; q < 4; ++q) {
                float2 f = __half22float2(hp[q]);
                #pragma unroll
                for (int h = 0; h < 4; ++h) {
                    acc[h][2 * q]     += a4[h] * f.x;
                    acc[h][2 * q + 1] += a4[h] * f.y;
                }
            }
        }

        // reduce across edge groups (lanes sharing cgrp); dsum rides along
        #pragma unroll
        for (int stride = LPE; stride < 64; stride <<= 1) {
            #pragma unroll
            for (int h = 0; h < 4; ++h) {
                #pragma unroll
                for (int r = 0; r < 8; ++r)
                    acc[h][r] += __shfl_xor(acc[h][r], stride);
                dsum[h] += __shfl_xor(dsum[h], stride);
            }
        }
        if (lane < LPE) {
            #pragma unroll
            for (int h = 0; h < 4; ++h) {
                float inv = 1.f / dsum[h];
                half8 v;
                #pragma unroll
                for (int r = 0; r < 8; ++r) v[r] = (_Float16)(acc[h][r] * inv);
                *(half8*)&As[nl][h * K + cgrp * 8] = v;
            }
        }
    }
    __syncthreads();

    // -------- phase 2: MFMA epilogue GEMM [32,KP]@[KP,128] --------
    int wm = wv >> 2, wn = wv & 3;
    int lr = lane & 15;
    int lk = (lane >> 4) * 8;
    int lg = lane >> 4;
    f32x4 acc2[2] = {};
    #pragma unroll
    for (int k0g = 0; k0g < NKg; ++k0g) {
        half8 af = *(const half8*)&As[wm * 16 + lr][k0g * 32 + lk];
        #pragma unroll
        for (int nn = 0; nn < 2; ++nn) {
            int cb = wn * 2 + nn;
            half8 bf = *(const half8*)(Wf + ((size_t)(cb * NKg + k0g) << 9) + lane * 8);
            acc2[nn] = __builtin_amdgcn_mfma_f32_16x16x32_f16(af, bf, acc2[nn], 0, 0, 0);
        }
    }
    __syncthreads();   // As fully consumed; tb may now overwrite it

    // epilogue: bias + BN + ReLU -> tb (aliases As)
    #pragma unroll
    for (int nn = 0; nn < 2; ++nn) {
        int col = wn * 32 + nn * 16 + lr;
        float b = bn_s[0][col], g = bn_s[1][col], be = bn_s[2][col];
        #pragma unroll
        for (int r = 0; r < 4; ++r) {
            float o = acc2[nn][r] + b;
            o = o * g + be;
            tb[wm * 16 + lg * 4 + r][col] = (_Float16)fmaxf(o, 0.f);
        }
    }
    __syncthreads();

    // coalesced h16 write: 32 rows x 128 cols
    {
        int row = t >> 4;
        int c0 = (t & 15) * 8;
        half8 v0 = *(const half8*)&tb[row][c0];
        *(half8*)((_Float16*)h16out + (size_t)(bm + row) * HID + c0) = v0;
    }

    // fused next-layer scores from output tile
    if (SCORES) {
        if (t < 256) {
            int node = t >> 3, j = t & 7;
            float sacc = 0.f;
            #pragma unroll 2
            for (int k0 = 0; k0 < HID; k0 += 8) {
                half8 hv = *(const half8*)&tb[node][k0];
                #pragma unroll
                for (int e = 0; e < 8; ++e)
                    sacc += (float)hv[e] * vs[(k0 + e) * 8 + j];
            }
            if (j < 4) ssrc_o[(bm + node) * 4 + j] = sacc;
            else       sdst_o[(bm + node) * 4 + (j - 4)] = sacc;
        }
    }
}

// ------- pooling: 2 nodes in flight, uint (2-channel) loads ----------------
__global__ __launch_bounds__(128) void pool_kernel(const __half* __restrict__ h,
                                                   const int* __restrict__ batch,
                                                   float* pooled, float* counts) {
    int t = threadIdx.x;
    int which = t >> 6;
    int c2 = (t & 63) * 2;
    int n0 = blockIdx.x * 256 + which;
    int n1 = min(blockIdx.x * 256 + 256, N_NODES);
    if (n0 >= N_NODES) return;
    int cg = batch[n0];
    float a0 = 0.f, a1 = 0.f, cnt = 0.f;
    for (int n = n0; n < n1; n += 2) {
        int g = batch[n];
        if (g != cg) {
            atomicAdd(&pooled[cg * HID + c2], a0);
            atomicAdd(&pooled[cg * HID + c2 + 1], a1);
            if ((t & 63) == 0) atomicAdd(&counts[cg], cnt);
            a0 = 0.f; a1 = 0.f; cnt = 0.f; cg = g;
        }
        uint u = *(const uint*)(h + (size_t)n * HID + c2);
        __half2 hh = *(__half2*)&u;
        float2 f = __half22float2(hh);
        a0 += f.x; a1 += f.y; cnt += 1.f;
    }
    atomicAdd(&pooled[cg * HID + c2], a0);
    atomicAdd(&pooled[cg * HID + c2 + 1], a1);
    if ((t & 63) == 0) atomicAdd(&counts[cg], cnt);
}

// ---------------- head: mean-divide + fc1 + relu + fc2 ----------------
__global__ __launch_bounds__(128) void head_kernel(const float* __restrict__ pooled,
                                                   const float* __restrict__ counts,
                                                   const float* __restrict__ fc1_w,
                                                   const float* __restrict__ fc1_b,
                                                   const float* __restrict__ fc2_w,
                                                   const float* __restrict__ fc2_b,
                                                   float* __restrict__ out) {
    int gI = blockIdx.x;
    int t = threadIdx.x;
    __shared__ float p[HID], hb[HID];
    p[t] = pooled[gI * HID + t] / fmaxf(counts[gI], 1.f);
    __syncthreads();
    float a = fc1_b[t];
    #pragma unroll 4
    for (int k = 0; k < HID; ++k) a += p[k] * fc1_w[k * HID + t];
    hb[t] = fmaxf(a, 0.f);
    __syncthreads();
    if (t < OUTDIM) {
        float o = fc2_b[t];
        #pragma unroll 4
        for (int k = 0; k < HID; ++k) o += hb[k] * fc2_w[k * OUTDIM + t];
        out[gI * OUTDIM + t] = o;
    }
}

extern "C" void kernel_launch(void* const* d_in, const int* in_sizes, int n_in,
                              void* d_out, int out_size, void* d_ws, size_t ws_size,
                              hipStream_t stream) {
    const float* x     = (const float*)d_in[0];
    const int*   ei    = (const int*)d_in[1];
    const int*   batch = (const int*)d_in[2];
    const float* W[3]  = {(const float*)d_in[3],  (const float*)d_in[9],  (const float*)d_in[15]};
    const float* As_[3] = {(const float*)d_in[4],  (const float*)d_in[10], (const float*)d_in[16]};
    const float* Ad[3] = {(const float*)d_in[5],  (const float*)d_in[11], (const float*)d_in[17]};
    const float* Bb[3] = {(const float*)d_in[6],  (const float*)d_in[12], (const float*)d_in[18]};
    const float* Gg[3] = {(const float*)d_in[7],  (const float*)d_in[13], (const float*)d_in[19]};
    const float* Be[3] = {(const float*)d_in[8],  (const float*)d_in[14], (const float*)d_in[20]};
    const float* fc1_w = (const float*)d_in[21];
    const float* fc1_b = (const float*)d_in[22];
    const float* fc2_w = (const float*)d_in[23];
    const float* fc2_b = (const float*)d_in[24];

    char* ws = (char*)d_ws;
    size_t off = 0;
    auto alloc = [&](size_t bytes) {
        void* p = ws + off;
        off = (off + bytes + 255) & ~(size_t)255;
        return p;
    };
    __half* x16    = (__half*)alloc((size_t)N_NODES * FIN * 2);
    __half* h16A   = (__half*)alloc((size_t)N_NODES * HID * 2);
    __half* h16B   = (__half*)alloc((size_t)N_NODES * HID * 2);
    _Float16* Wf[3];
    Wf[0] = (_Float16*)alloc((size_t)(4 * FIN) * HID * 2);
    Wf[1] = (_Float16*)alloc((size_t)(4 * HID) * HID * 2);
    Wf[2] = (_Float16*)alloc((size_t)(4 * HID) * HID * 2);
    float* vtab[3];
    vtab[0] = (float*)alloc((size_t)FIN * 8 * 4);
    vtab[1] = (float*)alloc((size_t)HID * 8 * 4);
    vtab[2] = (float*)alloc((size_t)HID * 8 * 4);
    float* ssrcA   = (float*)alloc((size_t)N_NODES * HEADS * 4);
    float* sdstA   = (float*)alloc((size_t)N_NODES * HEADS * 4);
    float* ssrcB   = (float*)alloc((size_t)N_NODES * HEADS * 4);
    float* sdstB   = (float*)alloc((size_t)N_NODES * HEADS * 4);
    float* val     = (float*)alloc((size_t)(N_EDGES + N_NODES) * 4 * 4);
    int*   deg     = (int*)alloc((size_t)N_NODES * 4);
    int*   offsets = (int*)alloc((size_t)(N_NODES + 1) * 4);
    int*   pos     = (int*)alloc((size_t)N_NODES * 4);
    int*   partial = (int*)alloc((size_t)256 * 4);
    int*   csr     = (int*)alloc((size_t)(N_EDGES + N_NODES) * 4);
    int*   csrd    = (int*)alloc((size_t)(N_EDGES + N_NODES) * 4);
    float* pooled  = (float*)alloc((size_t)NGROUPS * HID * 4 + (size_t)NGROUPS * 4);
    float* counts  = pooled + (size_t)NGROUPS * HID;

    // fused prep: x16 + fragment-major Wbig + vtab
    const int PREP_TOTAL = PREP_X4 + PREP_WSWZ + PREP_V;
    prep_kernel<<<(PREP_TOTAL + 255) / 256, 256, 0, stream>>>(
        x, x16, W[0], W[1], W[2], Wf[0], Wf[1], Wf[2],
        As_[0], Ad[0], As_[1], Ad[1], As_[2], Ad[2], vtab[0], vtab[1], vtab[2]);

    // CSR by dst (with self loops)
    const int NB = (N_NODES + 255) / 256;   // 157
    hipMemsetAsync(deg, 0, (size_t)N_NODES * 4, stream);
    deg_count_kernel<<<(N_EDGES + 255) / 256, 256, 0, stream>>>(ei, deg);
    scan1_kernel<<<NB, 256, 0, stream>>>(deg, offsets, partial);
    scan2_kernel<<<1, 256, 0, stream>>>(partial, NB);
    scan3_kernel<<<NB, 256, 0, stream>>>(offsets, pos, partial);
    scatter_kernel<<<(N_EDGES + N_NODES + 255) / 256, 256, 0, stream>>>(ei, pos, csr, csrd);

    const int EB = (N_EDGES + N_NODES + 255) / 256;

    // layer-0 scores from x16 -> A
    scores3_kernel<64><<<NB, 256, 0, stream>>>(x16, vtab[0], ssrcA, sdstA);

    // layer 0: edge vals (A) -> fused gather+GEMM, out h16A, scores B
    edge_val_kernel<<<EB, 256, 0, stream>>>(ssrcA, sdstA, csr, csrd, val);
    fused_layer_kernel<64, true><<<N_NODES / 32, 512, 0, stream>>>(
        x16, val, offsets, csr, Wf[0], Bb[0], Gg[0], Be[0],
        vtab[1], h16A, ssrcB, sdstB);
    // layer 1: edge vals (B) -> fused, out h16B, scores A
    edge_val_kernel<<<EB, 256, 0, stream>>>(ssrcB, sdstB, csr, csrd, val);
    fused_layer_kernel<128, true><<<N_NODES / 32, 512, 0, stream>>>(
        h16A, val, offsets, csr, Wf[1], Bb[1], Gg[1], Be[1],
        vtab[2], h16B, ssrcA, sdstA);
    // layer 2: edge vals (A) -> fused, out h16A, no score write
    edge_val_kernel<<<EB, 256, 0, stream>>>(ssrcA, sdstA, csr, csrd, val);
    fused_layer_kernel<128, false><<<N_NODES / 32, 512, 0, stream>>>(
        h16B, val, offsets, csr, Wf[2], Bb[2], Gg[2], Be[2],
        nullptr, h16A, nullptr, nullptr);

    // global mean pool + MLP head
    hipMemsetAsync(pooled, 0, (size_t)NGROUPS * HID * 4 + (size_t)NGROUPS * 4, stream);
    pool_kernel<<<(N_NODES + 255) / 256, 128, 0, stream>>>(h16A, batch, pooled, counts);
    head_kernel<<<NGROUPS, 128, 0, stream>>>(pooled, counts, fc1_w, fc1_b, fc2_w, fc2_b,
                                             (float*)d_out);
}

// Round 20
// 363.996 us; speedup vs baseline: 1.5731x; 1.0167x over previous
//
#include <hip/hip_runtime.h>
#include <hip/hip_fp16.h>
#include <math.h>

#define N_NODES 40000
#define N_EDGES 640000
#define FIN 64
#define HID 128
#define OUTDIM 64
#define HEADS 4
#define NGROUPS 64
#define NCOLS 512   // HEADS*HID

typedef _Float16 half8 __attribute__((ext_vector_type(8)));
typedef float f32x4 __attribute__((ext_vector_type(4)));

__device__ __forceinline__ float lrelu(float x) { return x > 0.f ? x : 0.2f * x; }

// ---- fused prep: x->fp16 | Wbig fragment-major swizzle (3 layers) | vtab ----
// Wbig_l[(h*K+k)][c] = 0.25 * W_l[k][h*128+c]  (head-mean folded in), fragment-major
#define PREP_X4   (N_NODES * FIN / 4)                 // 640000
#define PREP_WSWZ 20480                               // 4096 + 8192 + 8192
#define PREP_V    2560                                // (FIN + 2*HID) * 8
__global__ void prep_kernel(const float* __restrict__ x, __half* __restrict__ x16,
                            const float* __restrict__ W0, const float* __restrict__ W1,
                            const float* __restrict__ W2,
                            _Float16* __restrict__ F0, _Float16* __restrict__ F1,
                            _Float16* __restrict__ F2,
                            const float* __restrict__ as0, const float* __restrict__ ad0,
                            const float* __restrict__ as1, const float* __restrict__ ad1,
                            const float* __restrict__ as2, const float* __restrict__ ad2,
                            float* __restrict__ v0, float* __restrict__ v1,
                            float* __restrict__ v2) {
    int id = blockIdx.x * 256 + threadIdx.x;
    if (id < PREP_X4) {
        int i4 = id * 4;
        float4 v = *(const float4*)(x + i4);
        __half2 a = __floats2half2_rn(v.x, v.y);
        __half2 b = __floats2half2_rn(v.z, v.w);
        *(__half2*)(x16 + i4)     = a;
        *(__half2*)(x16 + i4 + 2) = b;
        return;
    }
    id -= PREP_X4;
    if (id < PREP_WSWZ) {
        const float* W; _Float16* F; int Kin;
        if (id < 4096)       { W = W0; F = F0; Kin = FIN; }
        else if (id < 12288) { W = W1; F = F1; Kin = HID; id -= 4096; }
        else                 { W = W2; F = F2; Kin = HID; id -= 12288; }
        int KP = Kin * 4;
        int NKg = KP / 32;
        int lane = id & 63;
        int blob = id >> 6;
        int k0g = blob % NKg;
        int cb  = blob / NKg;
        int col = cb * 16 + (lane & 15);
        int kkb = k0g * 32 + (lane >> 4) * 8;
        half8 v;
        #pragma unroll
        for (int e = 0; e < 8; ++e) {
            int kk = kkb + e;
            int k = kk & (Kin - 1);
            int h = kk / Kin;
            v[e] = (_Float16)(0.25f * W[(size_t)k * NCOLS + h * HID + col]);
        }
        *(half8*)(F + (size_t)blob * 512 + lane * 8) = v;
        return;
    }
    id -= PREP_WSWZ;
    if (id < PREP_V) {
        const float* W; const float* as_; const float* ad_; float* v; int j = id;
        if (j < FIN * 8)              { W = W0; as_ = as0; ad_ = ad0; v = v0; }
        else if (j < (FIN + HID) * 8) { W = W1; as_ = as1; ad_ = ad1; v = v1; j -= FIN * 8; }
        else                          { W = W2; as_ = as2; ad_ = ad2; v = v2; j -= (FIN + HID) * 8; }
        int k = j >> 3, sd = (j >> 2) & 1, h = j & 3;
        const float* av = sd ? ad_ : as_;
        float acc = 0.f;
        for (int c = 0; c < HID; ++c)
            acc += W[(size_t)k * NCOLS + h * HID + c] * av[h * HID + c];
        v[k * 8 + sd * 4 + h] = acc;
    }
}

// ---------------- CSR build ----------------
__global__ void deg_count_kernel(const int* __restrict__ ei, int* deg) {
    int e = blockIdx.x * blockDim.x + threadIdx.x;
    if (e < N_EDGES) atomicAdd(&deg[ei[N_EDGES + e]], 1);
}

__global__ void scan1_kernel(const int* __restrict__ deg, int* offsets, int* partial) {
    __shared__ int buf[256];
    int t = threadIdx.x;
    int i = blockIdx.x * 256 + t;
    int v = (i < N_NODES) ? deg[i] + 1 : 0;   // +1 = self loop
    buf[t] = v;
    __syncthreads();
    for (int off = 1; off < 256; off <<= 1) {
        int y = (t >= off) ? buf[t - off] : 0;
        __syncthreads();
        buf[t] += y;
        __syncthreads();
    }
    if (i < N_NODES) offsets[i] = buf[t] - v;
    if (t == 255) partial[blockIdx.x] = buf[255];
}

__global__ void scan2_kernel(int* partial, int nb) {
    __shared__ int buf[256];
    int t = threadIdx.x;
    int v = (t < nb) ? partial[t] : 0;
    buf[t] = v;
    __syncthreads();
    for (int off = 1; off < 256; off <<= 1) {
        int y = (t >= off) ? buf[t - off] : 0;
        __syncthreads();
        buf[t] += y;
        __syncthreads();
    }
    if (t < nb) partial[t] = buf[t] - v;
}

__global__ void scan3_kernel(int* offsets, int* pos, const int* __restrict__ partial) {
    int i = blockIdx.x * 256 + threadIdx.x;
    if (i < N_NODES) {
        int o = offsets[i] + partial[i >> 8];
        offsets[i] = o;
        pos[i] = o;
    }
    if (i == 0) offsets[N_NODES] = N_EDGES + N_NODES;
}

__global__ void scatter_kernel(const int* __restrict__ ei, int* pos,
                               int* csr_src, int* csr_dst) {
    int i = blockIdx.x * blockDim.x + threadIdx.x;
    if (i < N_EDGES) {
        int s = ei[i];
        int d = ei[N_EDGES + i];
        int p = atomicAdd(&pos[d], 1);
        csr_src[p] = s;
        csr_dst[p] = d;
    } else if (i < N_EDGES + N_NODES) {
        int nn = i - N_EDGES;
        int p = atomicAdd(&pos[nn], 1);
        csr_src[p] = nn;
        csr_dst[p] = nn;
    }
}

// ------- scores for layer 0: one THREAD per node, vtab in LDS ---------
template <int K>
__global__ __launch_bounds__(256) void scores3_kernel(const __half* __restrict__ x,
                                                      const float* __restrict__ v,
                                                      float* __restrict__ ssrc,
                                                      float* __restrict__ sdst) {
    __shared__ float vs[K * 8];
    int t = threadIdx.x;
    for (int i = t; i < K * 8; i += 256) vs[i] = v[i];
    __syncthreads();
    int node = blockIdx.x * 256 + t;
    if (node >= N_NODES) return;
    const __half* xr = x + (size_t)node * K;
    f32x4 as = {0.f, 0.f, 0.f, 0.f};
    f32x4 ad = {0.f, 0.f, 0.f, 0.f};
    #pragma unroll 4
    for (int k0 = 0; k0 < K; k0 += 8) {
        uint4 u = *(const uint4*)(xr + k0);
        __half2* hp = (__half2*)&u;
        #pragma unroll
        for (int q = 0; q < 4; ++q) {
            float2 f = __half22float2(hp[q]);
            int k = k0 + 2 * q;
            as += f.x * *(const f32x4*)&vs[k * 8];
            ad += f.x * *(const f32x4*)&vs[k * 8 + 4];
            as += f.y * *(const f32x4*)&vs[(k + 1) * 8];
            ad += f.y * *(const f32x4*)&vs[(k + 1) * 8 + 4];
        }
    }
    *(f32x4*)(ssrc + node * 4) = as;
    *(f32x4*)(sdst + node * 4) = ad;
}

// ------- edge-parallel softmax numerators, NO atomics -------
__global__ __launch_bounds__(256) void edge_val_kernel(const float* __restrict__ ssrc,
                                                       const float* __restrict__ sdst,
                                                       const int* __restrict__ csr_src,
                                                       const int* __restrict__ csr_dst,
                                                       float* __restrict__ val) {
    int j = blockIdx.x * 256 + threadIdx.x;
    if (j >= N_EDGES + N_NODES) return;
    int s = csr_src[j], d = csr_dst[j];
    float4 a = *(const float4*)(ssrc + s * 4);
    float4 b = *(const float4*)(sdst + d * 4);
    float4 v;
    v.x = __expf(lrelu(a.x + b.x));
    v.y = __expf(lrelu(a.y + b.y));
    v.z = __expf(lrelu(a.z + b.z));
    v.w = __expf(lrelu(a.w + b.w));
    *(float4*)(val + (size_t)j * 4) = v;
}

// ---- FUSED layer v6: 16 nodes/block, 256 threads, 4 waves (finer residency) ----
// Deferred-norm gather (2x unrolled) -> LDS As -> MFMA + BN/ReLU (+next scores).
// LDS ~22KB (K=128) -> ~7 blocks/CU; grid 2500 halves the tail quantum.
template <int K, bool SCORES>
__global__ __launch_bounds__(256) void fused_layer_kernel(
        const __half* __restrict__ tab16,
        const float* __restrict__ val,
        const int* __restrict__ offsets,
        const int* __restrict__ csr_src,
        const _Float16* __restrict__ Wf,
        const float* __restrict__ bias,
        const float* __restrict__ gamma,
        const float* __restrict__ beta,
        const float* __restrict__ vtab_next,
        __half* __restrict__ h16out,
        float* __restrict__ ssrc_o,
        float* __restrict__ sdst_o) {
    constexpr int KP = 4 * K;
    constexpr int EPR = (K == 128) ? 4 : 8;   // edges per gather round
    constexpr int LPE = 64 / EPR;             // lanes per edge
    constexpr int NKg = KP / 32;

    __shared__ _Float16 As[16][KP + 8];
    __shared__ float bn_s[3][HID];
    __shared__ float vs[SCORES ? HID * 8 : 8];
    _Float16 (*tb)[136] = (_Float16(*)[136])&As[0][0];   // aliases As (phase-2 only)

    int t = threadIdx.x;
    int lane = t & 63;
    int wv = t >> 6;          // 0..3
    int bm = blockIdx.x * 16;

    if (t < HID) {
        bn_s[0][t] = bias[t];
        bn_s[1][t] = gamma[t] * rsqrtf(1.f + 1e-5f);
        bn_s[2][t] = beta[t];
    }
    if (SCORES)
        for (int i = t; i < HID * 8; i += 256) vs[i] = vtab_next[i];

    int cgrp = lane & (LPE - 1);
    int egoff = lane / LPE;
    const char* xb = (const char*)tab16 + cgrp * 16;

    // -------- phase 1: gather 4 nodes per wave, 2 rounds in flight --------
    for (int i = 0; i < 4; ++i) {
        int nl = wv * 4 + i;
        int n = bm + nl;
        int start = offsets[n], end = offsets[n + 1];
        int deg = end - start;
        float acc[4][8] = {};
        f32x4 dsum = {0.f, 0.f, 0.f, 0.f};

        int j = 0;
        for (; j + 2 * EPR <= deg; j += 2 * EPR) {
            // both rounds fully in-range -> no masks
            int egA = start + j + egoff;
            int egB = egA + EPR;
            int srcA = csr_src[egA];
            int srcB = csr_src[egB];
            float4 vA = *(const float4*)(val + (size_t)egA * 4);
            float4 vB = *(const float4*)(val + (size_t)egB * 4);
            uint4 uA = *(const uint4*)(xb + (uint)srcA * (K * 2));
            uint4 uB = *(const uint4*)(xb + (uint)srcB * (K * 2));
            f32x4 aA = {vA.x, vA.y, vA.z, vA.w};
            f32x4 aB = {vB.x, vB.y, vB.z, vB.w};
            dsum += aA;
            dsum += aB;
            __half2* hA = (__half2*)&uA;
            __half2* hB = (__half2*)&uB;
            #pragma unroll
            for (int q = 0; q < 4; ++q) {
                float2 fA = __half22float2(hA[q]);
                float2 fB = __half22float2(hB[q]);
                #pragma unroll
                for (int h = 0; h < 4; ++h) {
                    acc[h][2 * q]     += aA[h] * fA.x + aB[h] * fB.x;
                    acc[h][2 * q + 1] += aA[h] * fA.y + aB[h] * fB.y;
                }
            }
        }
        for (; j < deg; j += EPR) {
            int eg = j + egoff;
            bool act = eg < deg;
            int ec = act ? eg : deg - 1;
            int src = csr_src[start + ec];
            float4 vv = *(const float4*)(val + (size_t)(start + ec) * 4);
            f32x4 a4;
            a4[0] = act ? vv.x : 0.f;
            a4[1] = act ? vv.y : 0.f;
            a4[2] = act ? vv.z : 0.f;
            a4[3] = act ? vv.w : 0.f;
            dsum += a4;
            uint4 u = *(const uint4*)(xb + (uint)src * (K * 2));
            __half2* hp = (__half2*)&u;
            #pragma unroll
            for (int q = 0; q < 4; ++q) {
                float2 f = __half22float2(hp[q]);
                #pragma unroll
                for (int h = 0; h < 4; ++h) {
                    acc[h][2 * q]     += a4[h] * f.x;
                    acc[h][2 * q + 1] += a4[h] * f.y;
                }
            }
        }

        // reduce across edge groups (lanes sharing cgrp); dsum rides along
        #pragma unroll
        for (int stride = LPE; stride < 64; stride <<= 1) {
            #pragma unroll
            for (int h = 0; h < 4; ++h) {
                #pragma unroll
                for (int r = 0; r < 8; ++r)
                    acc[h][r] += __shfl_xor(acc[h][r], stride);
                dsum[h] += __shfl_xor(dsum[h], stride);
            }
        }
        if (lane < LPE) {
            #pragma unroll
            for (int h = 0; h < 4; ++h) {
                float inv = 1.f / dsum[h];
                half8 v;
                #pragma unroll
                for (int r = 0; r < 8; ++r) v[r] = (_Float16)(acc[h][r] * inv);
                *(half8*)&As[nl][h * K + cgrp * 8] = v;
            }
        }
    }
    __syncthreads();

    // -------- phase 2: MFMA epilogue GEMM [16,KP]@[KP,128], wave wv owns 32 cols --
    int lr = lane & 15;
    int lk = (lane >> 4) * 8;
    int lg = lane >> 4;
    f32x4 acc2[2] = {};
    #pragma unroll
    for (int k0g = 0; k0g < NKg; ++k0g) {
        half8 af = *(const half8*)&As[lr][k0g * 32 + lk];
        #pragma unroll
        for (int nn = 0; nn < 2; ++nn) {
            int cb = wv * 2 + nn;
            half8 bf = *(const half8*)(Wf + ((size_t)(cb * NKg + k0g) << 9) + lane * 8);
            acc2[nn] = __builtin_amdgcn_mfma_f32_16x16x32_f16(af, bf, acc2[nn], 0, 0, 0);
        }
    }
    __syncthreads();   // As fully consumed; tb may now overwrite it

    // epilogue: bias + BN + ReLU -> tb (aliases As)
    #pragma unroll
    for (int nn = 0; nn < 2; ++nn) {
        int col = wv * 32 + nn * 16 + lr;
        float b = bn_s[0][col], g = bn_s[1][col], be = bn_s[2][col];
        #pragma unroll
        for (int r = 0; r < 4; ++r) {
            float o = acc2[nn][r] + b;
            o = o * g + be;
            tb[lg * 4 + r][col] = (_Float16)fmaxf(o, 0.f);
        }
    }
    __syncthreads();

    // coalesced h16 write: 16 rows x 128 cols (256 threads x half8)
    {
        int row = t >> 4;
        int c0 = (t & 15) * 8;
        half8 v0 = *(const half8*)&tb[row][c0];
        *(half8*)((_Float16*)h16out + (size_t)(bm + row) * HID + c0) = v0;
    }

    // fused next-layer scores from output tile (16 nodes x 8 j = 128 threads)
    if (SCORES) {
        if (t < 128) {
            int node = t >> 3, j = t & 7;
            float sacc = 0.f;
            #pragma unroll 2
            for (int k0 = 0; k0 < HID; k0 += 8) {
                half8 hv = *(const half8*)&tb[node][k0];
                #pragma unroll
                for (int e = 0; e < 8; ++e)
                    sacc += (float)hv[e] * vs[(k0 + e) * 8 + j];
            }
            if (j < 4) ssrc_o[(bm + node) * 4 + j] = sacc;
            else       sdst_o[(bm + node) * 4 + (j - 4)] = sacc;
        }
    }
}

// ------- pooling: 2 nodes in flight, uint (2-channel) loads ----------------
__global__ __launch_bounds__(128) void pool_kernel(const __half* __restrict__ h,
                                                   const int* __restrict__ batch,
                                                   float* pooled, float* counts) {
    int t = threadIdx.x;
    int which = t >> 6;
    int c2 = (t & 63) * 2;
    int n0 = blockIdx.x * 256 + which;
    int n1 = min(blockIdx.x * 256 + 256, N_NODES);
    if (n0 >= N_NODES) return;
    int cg = batch[n0];
    float a0 = 0.f, a1 = 0.f, cnt = 0.f;
    for (int n = n0; n < n1; n += 2) {
        int g = batch[n];
        if (g != cg) {
            atomicAdd(&pooled[cg * HID + c2], a0);
            atomicAdd(&pooled[cg * HID + c2 + 1], a1);
            if ((t & 63) == 0) atomicAdd(&counts[cg], cnt);
            a0 = 0.f; a1 = 0.f; cnt = 0.f; cg = g;
        }
        uint u = *(const uint*)(h + (size_t)n * HID + c2);
        __half2 hh = *(__half2*)&u;
        float2 f = __half22float2(hh);
        a0 += f.x; a1 += f.y; cnt += 1.f;
    }
    atomicAdd(&pooled[cg * HID + c2], a0);
    atomicAdd(&pooled[cg * HID + c2 + 1], a1);
    if ((t & 63) == 0) atomicAdd(&counts[cg], cnt);
}

// ---------------- head: mean-divide + fc1 + relu + fc2 ----------------
__global__ __launch_bounds__(128) void head_kernel(const float* __restrict__ pooled,
                                                   const float* __restrict__ counts,
                                                   const float* __restrict__ fc1_w,
                                                   const float* __restrict__ fc1_b,
                                                   const float* __restrict__ fc2_w,
                                                   const float* __restrict__ fc2_b,
                                                   float* __restrict__ out) {
    int gI = blockIdx.x;
    int t = threadIdx.x;
    __shared__ float p[HID], hb[HID];
    p[t] = pooled[gI * HID + t] / fmaxf(counts[gI], 1.f);
    __syncthreads();
    float a = fc1_b[t];
    #pragma unroll 4
    for (int k = 0; k < HID; ++k) a += p[k] * fc1_w[k * HID + t];
    hb[t] = fmaxf(a, 0.f);
    __syncthreads();
    if (t < OUTDIM) {
        float o = fc2_b[t];
        #pragma unroll 4
        for (int k = 0; k < HID; ++k) o += hb[k] * fc2_w[k * OUTDIM + t];
        out[gI * OUTDIM + t] = o;
    }
}

extern "C" void kernel_launch(void* const* d_in, const int* in_sizes, int n_in,
                              void* d_out, int out_size, void* d_ws, size_t ws_size,
                              hipStream_t stream) {
    const float* x     = (const float*)d_in[0];
    const int*   ei    = (const int*)d_in[1];
    const int*   batch = (const int*)d_in[2];
    const float* W[3]  = {(const float*)d_in[3],  (const float*)d_in[9],  (const float*)d_in[15]};
    const float* As_[3] = {(const float*)d_in[4],  (const float*)d_in[10], (const float*)d_in[16]};
    const float* Ad[3] = {(const float*)d_in[5],  (const float*)d_in[11], (const float*)d_in[17]};
    const float* Bb[3] = {(const float*)d_in[6],  (const float*)d_in[12], (const float*)d_in[18]};
    const float* Gg[3] = {(const float*)d_in[7],  (const float*)d_in[13], (const float*)d_in[19]};
    const float* Be[3] = {(const float*)d_in[8],  (const float*)d_in[14], (const float*)d_in[20]};
    const float* fc1_w = (const float*)d_in[21];
    const float* fc1_b = (const float*)d_in[22];
    const float* fc2_w = (const float*)d_in[23];
    const float* fc2_b = (const float*)d_in[24];

    char* ws = (char*)d_ws;
    size_t off = 0;
    auto alloc = [&](size_t bytes) {
        void* p = ws + off;
        off = (off + bytes + 255) & ~(size_t)255;
        return p;
    };
    __half* x16    = (__half*)alloc((size_t)N_NODES * FIN * 2);
    __half* h16A   = (__half*)alloc((size_t)N_NODES * HID * 2);
    __half* h16B   = (__half*)alloc((size_t)N_NODES * HID * 2);
    _Float16* Wf[3];
    Wf[0] = (_Float16*)alloc((size_t)(4 * FIN) * HID * 2);
    Wf[1] = (_Float16*)alloc((size_t)(4 * HID) * HID * 2);
    Wf[2] = (_Float16*)alloc((size_t)(4 * HID) * HID * 2);
    float* vtab[3];
    vtab[0] = (float*)alloc((size_t)FIN * 8 * 4);
    vtab[1] = (float*)alloc((size_t)HID * 8 * 4);
    vtab[2] = (float*)alloc((size_t)HID * 8 * 4);
    float* ssrcA   = (float*)alloc((size_t)N_NODES * HEADS * 4);
    float* sdstA   = (float*)alloc((size_t)N_NODES * HEADS * 4);
    float* ssrcB   = (float*)alloc((size_t)N_NODES * HEADS * 4);
    float* sdstB   = (float*)alloc((size_t)N_NODES * HEADS * 4);
    float* val     = (float*)alloc((size_t)(N_EDGES + N_NODES) * 4 * 4);
    int*   deg     = (int*)alloc((size_t)N_NODES * 4);
    int*   offsets = (int*)alloc((size_t)(N_NODES + 1) * 4);
    int*   pos     = (int*)alloc((size_t)N_NODES * 4);
    int*   partial = (int*)alloc((size_t)256 * 4);
    int*   csr     = (int*)alloc((size_t)(N_EDGES + N_NODES) * 4);
    int*   csrd    = (int*)alloc((size_t)(N_EDGES + N_NODES) * 4);
    float* pooled  = (float*)alloc((size_t)NGROUPS * HID * 4 + (size_t)NGROUPS * 4);
    float* counts  = pooled + (size_t)NGROUPS * HID;

    // fused prep: x16 + fragment-major Wbig + vtab
    const int PREP_TOTAL = PREP_X4 + PREP_WSWZ + PREP_V;
    prep_kernel<<<(PREP_TOTAL + 255) / 256, 256, 0, stream>>>(
        x, x16, W[0], W[1], W[2], Wf[0], Wf[1], Wf[2],
        As_[0], Ad[0], As_[1], Ad[1], As_[2], Ad[2], vtab[0], vtab[1], vtab[2]);

    // CSR by dst (with self loops)
    const int NB = (N_NODES + 255) / 256;   // 157
    hipMemsetAsync(deg, 0, (size_t)N_NODES * 4, stream);
    deg_count_kernel<<<(N_EDGES + 255) / 256, 256, 0, stream>>>(ei, deg);
    scan1_kernel<<<NB, 256, 0, stream>>>(deg, offsets, partial);
    scan2_kernel<<<1, 256, 0, stream>>>(partial, NB);
    scan3_kernel<<<NB, 256, 0, stream>>>(offsets, pos, partial);
    scatter_kernel<<<(N_EDGES + N_NODES + 255) / 256, 256, 0, stream>>>(ei, pos, csr, csrd);

    const int EB = (N_EDGES + N_NODES + 255) / 256;

    // layer-0 scores from x16 -> A
    scores3_kernel<64><<<NB, 256, 0, stream>>>(x16, vtab[0], ssrcA, sdstA);

    // layer 0: edge vals (A) -> fused gather+GEMM, out h16A, scores B
    edge_val_kernel<<<EB, 256, 0, stream>>>(ssrcA, sdstA, csr, csrd, val);
    fused_layer_kernel<64, true><<<N_NODES / 16, 256, 0, stream>>>(
        x16, val, offsets, csr, Wf[0], Bb[0], Gg[0], Be[0],
        vtab[1], h16A, ssrcB, sdstB);
    // layer 1: edge vals (B) -> fused, out h16B, scores A
    edge_val_kernel<<<EB, 256, 0, stream>>>(ssrcB, sdstB, csr, csrd, val);
    fused_layer_kernel<128, true><<<N_NODES / 16, 256, 0, stream>>>(
        h16A, val, offsets, csr, Wf[1], Bb[1], Gg[1], Be[1],
        vtab[2], h16B, ssrcA, sdstA);
    // layer 2: edge vals (A) -> fused, out h16A, no score write
    edge_val_kernel<<<EB, 256, 0, stream>>>(ssrcA, sdstA, csr, csrd, val);
    fused_layer_kernel<128, false><<<N_NODES / 16, 256, 0, stream>>>(
        h16B, val, offsets, csr, Wf[2], Bb[2], Gg[2], Be[2],
        nullptr, h16A, nullptr, nullptr);

    // global mean pool + MLP head
    hipMemsetAsync(pooled, 0, (size_t)NGROUPS * HID * 4 + (size_t)NGROUPS * 4, stream);
    pool_kernel<<<(N_NODES + 255) / 256, 128, 0, stream>>>(h16A, batch, pooled, counts);
    head_kernel<<<NGROUPS, 128, 0, stream>>>(pooled, counts, fc1_w, fc1_b, fc2_w, fc2_b,
                                             (float*)d_out);
}

// Round 21
// 362.479 us; speedup vs baseline: 1.5797x; 1.0042x over previous
//
#include <hip/hip_runtime.h>
#include <hip/hip_fp16.h>
#include <math.h>

#define N_NODES 40000
#define N_EDGES 640000
#define FIN 64
#define HID 128
#define OUTDIM 64
#define HEADS 4
#define NGROUPS 64
#define NCOLS 512   // HEADS*HID

typedef _Float16 half8 __attribute__((ext_vector_type(8)));
typedef float f32x4 __attribute__((ext_vector_type(4)));

__device__ __forceinline__ float lrelu(float x) { return x > 0.f ? x : 0.2f * x; }

// ---- fused prep: x->fp16 | Wbig fragment-major swizzle (3 layers) | vtab ----
// Wbig_l[(h*K+k)][c] = 0.25 * W_l[k][h*128+c]  (head-mean folded in), fragment-major
#define PREP_X4   (N_NODES * FIN / 4)                 // 640000
#define PREP_WSWZ 20480                               // 4096 + 8192 + 8192
#define PREP_V    2560                                // (FIN + 2*HID) * 8
__global__ void prep_kernel(const float* __restrict__ x, __half* __restrict__ x16,
                            const float* __restrict__ W0, const float* __restrict__ W1,
                            const float* __restrict__ W2,
                            _Float16* __restrict__ F0, _Float16* __restrict__ F1,
                            _Float16* __restrict__ F2,
                            const float* __restrict__ as0, const float* __restrict__ ad0,
                            const float* __restrict__ as1, const float* __restrict__ ad1,
                            const float* __restrict__ as2, const float* __restrict__ ad2,
                            float* __restrict__ v0, float* __restrict__ v1,
                            float* __restrict__ v2) {
    int id = blockIdx.x * 256 + threadIdx.x;
    if (id < PREP_X4) {
        int i4 = id * 4;
        float4 v = *(const float4*)(x + i4);
        __half2 a = __floats2half2_rn(v.x, v.y);
        __half2 b = __floats2half2_rn(v.z, v.w);
        *(__half2*)(x16 + i4)     = a;
        *(__half2*)(x16 + i4 + 2) = b;
        return;
    }
    id -= PREP_X4;
    if (id < PREP_WSWZ) {
        const float* W; _Float16* F; int Kin;
        if (id < 4096)       { W = W0; F = F0; Kin = FIN; }
        else if (id < 12288) { W = W1; F = F1; Kin = HID; id -= 4096; }
        else                 { W = W2; F = F2; Kin = HID; id -= 12288; }
        int KP = Kin * 4;
        int NKg = KP / 32;
        int lane = id & 63;
        int blob = id >> 6;
        int k0g = blob % NKg;
        int cb  = blob / NKg;
        int col = cb * 16 + (lane & 15);
        int kkb = k0g * 32 + (lane >> 4) * 8;
        half8 v;
        #pragma unroll
        for (int e = 0; e < 8; ++e) {
            int kk = kkb + e;
            int k = kk & (Kin - 1);
            int h = kk / Kin;
            v[e] = (_Float16)(0.25f * W[(size_t)k * NCOLS + h * HID + col]);
        }
        *(half8*)(F + (size_t)blob * 512 + lane * 8) = v;
        return;
    }
    id -= PREP_WSWZ;
    if (id < PREP_V) {
        const float* W; const float* as_; const float* ad_; float* v; int j = id;
        if (j < FIN * 8)              { W = W0; as_ = as0; ad_ = ad0; v = v0; }
        else if (j < (FIN + HID) * 8) { W = W1; as_ = as1; ad_ = ad1; v = v1; j -= FIN * 8; }
        else                          { W = W2; as_ = as2; ad_ = ad2; v = v2; j -= (FIN + HID) * 8; }
        int k = j >> 3, sd = (j >> 2) & 1, h = j & 3;
        const float* av = sd ? ad_ : as_;
        float acc = 0.f;
        for (int c = 0; c < HID; ++c)
            acc += W[(size_t)k * NCOLS + h * HID + c] * av[h * HID + c];
        v[k * 8 + sd * 4 + h] = acc;
    }
}

// ---------------- CSR build ----------------
__global__ void deg_count_kernel(const int* __restrict__ ei, int* deg) {
    int e = blockIdx.x * blockDim.x + threadIdx.x;
    if (e < N_EDGES) atomicAdd(&deg[ei[N_EDGES + e]], 1);
}

__global__ void scan1_kernel(const int* __restrict__ deg, int* offsets, int* partial) {
    __shared__ int buf[256];
    int t = threadIdx.x;
    int i = blockIdx.x * 256 + t;
    int v = (i < N_NODES) ? deg[i] + 1 : 0;   // +1 = self loop
    buf[t] = v;
    __syncthreads();
    for (int off = 1; off < 256; off <<= 1) {
        int y = (t >= off) ? buf[t - off] : 0;
        __syncthreads();
        buf[t] += y;
        __syncthreads();
    }
    if (i < N_NODES) offsets[i] = buf[t] - v;
    if (t == 255) partial[blockIdx.x] = buf[255];
}

__global__ void scan2_kernel(int* partial, int nb) {
    __shared__ int buf[256];
    int t = threadIdx.x;
    int v = (t < nb) ? partial[t] : 0;
    buf[t] = v;
    __syncthreads();
    for (int off = 1; off < 256; off <<= 1) {
        int y = (t >= off) ? buf[t - off] : 0;
        __syncthreads();
        buf[t] += y;
        __syncthreads();
    }
    if (t < nb) partial[t] = buf[t] - v;
}

__global__ void scan3_kernel(int* offsets, int* pos, const int* __restrict__ partial) {
    int i = blockIdx.x * 256 + threadIdx.x;
    if (i < N_NODES) {
        int o = offsets[i] + partial[i >> 8];
        offsets[i] = o;
        pos[i] = o;
    }
    if (i == 0) offsets[N_NODES] = N_EDGES + N_NODES;
}

__global__ void scatter_kernel(const int* __restrict__ ei, int* pos, int* csr_src) {
    int i = blockIdx.x * blockDim.x + threadIdx.x;
    if (i < N_EDGES) {
        int s = ei[i];
        int d = ei[N_EDGES + i];
        csr_src[atomicAdd(&pos[d], 1)] = s;
    } else if (i < N_EDGES + N_NODES) {
        int nn = i - N_EDGES;
        csr_src[atomicAdd(&pos[nn], 1)] = nn;
    }
}

// ------- scores for layer 0: one THREAD per node, vtab in LDS ---------
template <int K>
__global__ __launch_bounds__(256) void scores3_kernel(const __half* __restrict__ x,
                                                      const float* __restrict__ v,
                                                      float* __restrict__ ssrc,
                                                      float* __restrict__ sdst) {
    __shared__ float vs[K * 8];
    int t = threadIdx.x;
    for (int i = t; i < K * 8; i += 256) vs[i] = v[i];
    __syncthreads();
    int node = blockIdx.x * 256 + t;
    if (node >= N_NODES) return;
    const __half* xr = x + (size_t)node * K;
    f32x4 as = {0.f, 0.f, 0.f, 0.f};
    f32x4 ad = {0.f, 0.f, 0.f, 0.f};
    #pragma unroll 4
    for (int k0 = 0; k0 < K; k0 += 8) {
        uint4 u = *(const uint4*)(xr + k0);
        __half2* hp = (__half2*)&u;
        #pragma unroll
        for (int q = 0; q < 4; ++q) {
            float2 f = __half22float2(hp[q]);
            int k = k0 + 2 * q;
            as += f.x * *(const f32x4*)&vs[k * 8];
            ad += f.x * *(const f32x4*)&vs[k * 8 + 4];
            as += f.y * *(const f32x4*)&vs[(k + 1) * 8];
            ad += f.y * *(const f32x4*)&vs[(k + 1) * 8 + 4];
        }
    }
    *(f32x4*)(ssrc + node * 4) = as;
    *(f32x4*)(sdst + node * 4) = ad;
}

// ---- FUSED layer v7: 16 nodes/block, inline softmax numerators (no edge_val) ----
// val_j = exp(lrelu(ssrc[src_j] + sdst[n])) computed in-loop; ssrc is a 640KB
// L2-resident table (16B gathers, same chain depth as the old val load).
// Deferred normalization: acc = (sum val_j x_j) * (1/sum val_j).
// NO min-waves launch-bounds pin (r18 lesson: pinning caused 32-VGPR spills).
template <int K, bool SCORES>
__global__ __launch_bounds__(256) void fused_layer_kernel(
        const __half* __restrict__ tab16,
        const float* __restrict__ s_src,
        const float* __restrict__ s_dst,
        const int* __restrict__ offsets,
        const int* __restrict__ csr_src,
        const _Float16* __restrict__ Wf,
        const float* __restrict__ bias,
        const float* __restrict__ gamma,
        const float* __restrict__ beta,
        const float* __restrict__ vtab_next,
        __half* __restrict__ h16out,
        float* __restrict__ ssrc_o,
        float* __restrict__ sdst_o) {
    constexpr int KP = 4 * K;
    constexpr int EPR = (K == 128) ? 4 : 8;   // edges per gather round
    constexpr int LPE = 64 / EPR;             // lanes per edge
    constexpr int NKg = KP / 32;

    __shared__ _Float16 As[16][KP + 8];
    __shared__ float bn_s[3][HID];
    __shared__ float vs[SCORES ? HID * 8 : 8];
    _Float16 (*tb)[136] = (_Float16(*)[136])&As[0][0];   // aliases As (phase-2 only)

    int t = threadIdx.x;
    int lane = t & 63;
    int wv = t >> 6;          // 0..3
    int bm = blockIdx.x * 16;

    if (t < HID) {
        bn_s[0][t] = bias[t];
        bn_s[1][t] = gamma[t] * rsqrtf(1.f + 1e-5f);
        bn_s[2][t] = beta[t];
    }
    if (SCORES)
        for (int i = t; i < HID * 8; i += 256) vs[i] = vtab_next[i];

    int cgrp = lane & (LPE - 1);
    int egoff = lane / LPE;
    const char* xb = (const char*)tab16 + cgrp * 16;

    // -------- phase 1: gather 4 nodes per wave, 2 rounds in flight --------
    for (int i = 0; i < 4; ++i) {
        int nl = wv * 4 + i;
        int n = bm + nl;
        int start = offsets[n], end = offsets[n + 1];
        int deg = end - start;
        const float4 sd = *(const float4*)(s_dst + n * 4);
        float acc[4][8] = {};
        f32x4 dsum = {0.f, 0.f, 0.f, 0.f};

        int j = 0;
        for (; j + 2 * EPR <= deg; j += 2 * EPR) {
            // both rounds fully in-range -> no masks
            int egA = start + j + egoff;
            int egB = egA + EPR;
            int srcA = csr_src[egA];
            int srcB = csr_src[egB];
            float4 qA = *(const float4*)(s_src + srcA * 4);
            float4 qB = *(const float4*)(s_src + srcB * 4);
            uint4 uA = *(const uint4*)(xb + (uint)srcA * (K * 2));
            uint4 uB = *(const uint4*)(xb + (uint)srcB * (K * 2));
            f32x4 aA, aB;
            aA[0] = __expf(lrelu(qA.x + sd.x));
            aA[1] = __expf(lrelu(qA.y + sd.y));
            aA[2] = __expf(lrelu(qA.z + sd.z));
            aA[3] = __expf(lrelu(qA.w + sd.w));
            aB[0] = __expf(lrelu(qB.x + sd.x));
            aB[1] = __expf(lrelu(qB.y + sd.y));
            aB[2] = __expf(lrelu(qB.z + sd.z));
            aB[3] = __expf(lrelu(qB.w + sd.w));
            dsum += aA;
            dsum += aB;
            __half2* hA = (__half2*)&uA;
            __half2* hB = (__half2*)&uB;
            #pragma unroll
            for (int q = 0; q < 4; ++q) {
                float2 fA = __half22float2(hA[q]);
                float2 fB = __half22float2(hB[q]);
                #pragma unroll
                for (int h = 0; h < 4; ++h) {
                    acc[h][2 * q]     += aA[h] * fA.x + aB[h] * fB.x;
                    acc[h][2 * q + 1] += aA[h] * fA.y + aB[h] * fB.y;
                }
            }
        }
        for (; j < deg; j += EPR) {
            int eg = j + egoff;
            bool act = eg < deg;
            int ec = act ? eg : deg - 1;
            int src = csr_src[start + ec];
            float4 qq = *(const float4*)(s_src + src * 4);
            f32x4 a4;
            a4[0] = act ? __expf(lrelu(qq.x + sd.x)) : 0.f;
            a4[1] = act ? __expf(lrelu(qq.y + sd.y)) : 0.f;
            a4[2] = act ? __expf(lrelu(qq.z + sd.z)) : 0.f;
            a4[3] = act ? __expf(lrelu(qq.w + sd.w)) : 0.f;
            dsum += a4;
            uint4 u = *(const uint4*)(xb + (uint)src * (K * 2));
            __half2* hp = (__half2*)&u;
            #pragma unroll
            for (int q = 0; q < 4; ++q) {
                float2 f = __half22float2(hp[q]);
                #pragma unroll
                for (int h = 0; h < 4; ++h) {
                    acc[h][2 * q]     += a4[h] * f.x;
                    acc[h][2 * q + 1] += a4[h] * f.y;
                }
            }
        }

        // reduce across edge groups (lanes sharing cgrp); dsum rides along
        #pragma unroll
        for (int stride = LPE; stride < 64; stride <<= 1) {
            #pragma unroll
            for (int h = 0; h < 4; ++h) {
                #pragma unroll
                for (int r = 0; r < 8; ++r)
                    acc[h][r] += __shfl_xor(acc[h][r], stride);
                dsum[h] += __shfl_xor(dsum[h], stride);
            }
        }
        if (lane < LPE) {
            #pragma unroll
            for (int h = 0; h < 4; ++h) {
                float inv = 1.f / dsum[h];
                half8 v;
                #pragma unroll
                for (int r = 0; r < 8; ++r) v[r] = (_Float16)(acc[h][r] * inv);
                *(half8*)&As[nl][h * K + cgrp * 8] = v;
            }
        }
    }
    __syncthreads();

    // -------- phase 2: MFMA epilogue GEMM [16,KP]@[KP,128], wave wv owns 32 cols --
    int lr = lane & 15;
    int lk = (lane >> 4) * 8;
    int lg = lane >> 4;
    f32x4 acc2[2] = {};
    #pragma unroll
    for (int k0g = 0; k0g < NKg; ++k0g) {
        half8 af = *(const half8*)&As[lr][k0g * 32 + lk];
        #pragma unroll
        for (int nn = 0; nn < 2; ++nn) {
            int cb = wv * 2 + nn;
            half8 bf = *(const half8*)(Wf + ((size_t)(cb * NKg + k0g) << 9) + lane * 8);
            acc2[nn] = __builtin_amdgcn_mfma_f32_16x16x32_f16(af, bf, acc2[nn], 0, 0, 0);
        }
    }
    __syncthreads();   // As fully consumed; tb may now overwrite it

    // epilogue: bias + BN + ReLU -> tb (aliases As)
    #pragma unroll
    for (int nn = 0; nn < 2; ++nn) {
        int col = wv * 32 + nn * 16 + lr;
        float b = bn_s[0][col], g = bn_s[1][col], be = bn_s[2][col];
        #pragma unroll
        for (int r = 0; r < 4; ++r) {
            float o = acc2[nn][r] + b;
            o = o * g + be;
            tb[lg * 4 + r][col] = (_Float16)fmaxf(o, 0.f);
        }
    }
    __syncthreads();

    // coalesced h16 write: 16 rows x 128 cols (256 threads x half8)
    {
        int row = t >> 4;
        int c0 = (t & 15) * 8;
        half8 v0 = *(const half8*)&tb[row][c0];
        *(half8*)((_Float16*)h16out + (size_t)(bm + row) * HID + c0) = v0;
    }

    // fused next-layer scores from output tile (16 nodes x 8 j = 128 threads)
    if (SCORES) {
        if (t < 128) {
            int node = t >> 3, j = t & 7;
            float sacc = 0.f;
            #pragma unroll 2
            for (int k0 = 0; k0 < HID; k0 += 8) {
                half8 hv = *(const half8*)&tb[node][k0];
                #pragma unroll
                for (int e = 0; e < 8; ++e)
                    sacc += (float)hv[e] * vs[(k0 + e) * 8 + j];
            }
            if (j < 4) ssrc_o[(bm + node) * 4 + j] = sacc;
            else       sdst_o[(bm + node) * 4 + (j - 4)] = sacc;
        }
    }
}

// ------- pooling: 2 nodes in flight, uint (2-channel) loads ----------------
__global__ __launch_bounds__(128) void pool_kernel(const __half* __restrict__ h,
                                                   const int* __restrict__ batch,
                                                   float* pooled, float* counts) {
    int t = threadIdx.x;
    int which = t >> 6;
    int c2 = (t & 63) * 2;
    int n0 = blockIdx.x * 256 + which;
    int n1 = min(blockIdx.x * 256 + 256, N_NODES);
    if (n0 >= N_NODES) return;
    int cg = batch[n0];
    float a0 = 0.f, a1 = 0.f, cnt = 0.f;
    for (int n = n0; n < n1; n += 2) {
        int g = batch[n];
        if (g != cg) {
            atomicAdd(&pooled[cg * HID + c2], a0);
            atomicAdd(&pooled[cg * HID + c2 + 1], a1);
            if ((t & 63) == 0) atomicAdd(&counts[cg], cnt);
            a0 = 0.f; a1 = 0.f; cnt = 0.f; cg = g;
        }
        uint u = *(const uint*)(h + (size_t)n * HID + c2);
        __half2 hh = *(__half2*)&u;
        float2 f = __half22float2(hh);
        a0 += f.x; a1 += f.y; cnt += 1.f;
    }
    atomicAdd(&pooled[cg * HID + c2], a0);
    atomicAdd(&pooled[cg * HID + c2 + 1], a1);
    if ((t & 63) == 0) atomicAdd(&counts[cg], cnt);
}

// ---------------- head: mean-divide + fc1 + relu + fc2 ----------------
__global__ __launch_bounds__(128) void head_kernel(const float* __restrict__ pooled,
                                                   const float* __restrict__ counts,
                                                   const float* __restrict__ fc1_w,
                                                   const float* __restrict__ fc1_b,
                                                   const float* __restrict__ fc2_w,
                                                   const float* __restrict__ fc2_b,
                                                   float* __restrict__ out) {
    int gI = blockIdx.x;
    int t = threadIdx.x;
    __shared__ float p[HID], hb[HID];
    p[t] = pooled[gI * HID + t] / fmaxf(counts[gI], 1.f);
    __syncthreads();
    float a = fc1_b[t];
    #pragma unroll 4
    for (int k = 0; k < HID; ++k) a += p[k] * fc1_w[k * HID + t];
    hb[t] = fmaxf(a, 0.f);
    __syncthreads();
    if (t < OUTDIM) {
        float o = fc2_b[t];
        #pragma unroll 4
        for (int k = 0; k < HID; ++k) o += hb[k] * fc2_w[k * OUTDIM + t];
        out[gI * OUTDIM + t] = o;
    }
}

extern "C" void kernel_launch(void* const* d_in, const int* in_sizes, int n_in,
                              void* d_out, int out_size, void* d_ws, size_t ws_size,
                              hipStream_t stream) {
    const float* x     = (const float*)d_in[0];
    const int*   ei    = (const int*)d_in[1];
    const int*   batch = (const int*)d_in[2];
    const float* W[3]  = {(const float*)d_in[3],  (const float*)d_in[9],  (const float*)d_in[15]};
    const float* As_[3] = {(const float*)d_in[4],  (const float*)d_in[10], (const float*)d_in[16]};
    const float* Ad[3] = {(const float*)d_in[5],  (const float*)d_in[11], (const float*)d_in[17]};
    const float* Bb[3] = {(const float*)d_in[6],  (const float*)d_in[12], (const float*)d_in[18]};
    const float* Gg[3] = {(const float*)d_in[7],  (const float*)d_in[13], (const float*)d_in[19]};
    const float* Be[3] = {(const float*)d_in[8],  (const float*)d_in[14], (const float*)d_in[20]};
    const float* fc1_w = (const float*)d_in[21];
    const float* fc1_b = (const float*)d_in[22];
    const float* fc2_w = (const float*)d_in[23];
    const float* fc2_b = (const float*)d_in[24];

    char* ws = (char*)d_ws;
    size_t off = 0;
    auto alloc = [&](size_t bytes) {
        void* p = ws + off;
        off = (off + bytes + 255) & ~(size_t)255;
        return p;
    };
    __half* x16    = (__half*)alloc((size_t)N_NODES * FIN * 2);
    __half* h16A   = (__half*)alloc((size_t)N_NODES * HID * 2);
    __half* h16B   = (__half*)alloc((size_t)N_NODES * HID * 2);
    _Float16* Wf[3];
    Wf[0] = (_Float16*)alloc((size_t)(4 * FIN) * HID * 2);
    Wf[1] = (_Float16*)alloc((size_t)(4 * HID) * HID * 2);
    Wf[2] = (_Float16*)alloc((size_t)(4 * HID) * HID * 2);
    float* vtab[3];
    vtab[0] = (float*)alloc((size_t)FIN * 8 * 4);
    vtab[1] = (float*)alloc((size_t)HID * 8 * 4);
    vtab[2] = (float*)alloc((size_t)HID * 8 * 4);
    float* ssrcA   = (float*)alloc((size_t)N_NODES * HEADS * 4);
    float* sdstA   = (float*)alloc((size_t)N_NODES * HEADS * 4);
    float* ssrcB   = (float*)alloc((size_t)N_NODES * HEADS * 4);
    float* sdstB   = (float*)alloc((size_t)N_NODES * HEADS * 4);
    int*   deg     = (int*)alloc((size_t)N_NODES * 4);
    int*   offsets = (int*)alloc((size_t)(N_NODES + 1) * 4);
    int*   pos     = (int*)alloc((size_t)N_NODES * 4);
    int*   partial = (int*)alloc((size_t)256 * 4);
    int*   csr     = (int*)alloc((size_t)(N_EDGES + N_NODES) * 4);
    float* pooled  = (float*)alloc((size_t)NGROUPS * HID * 4 + (size_t)NGROUPS * 4);
    float* counts  = pooled + (size_t)NGROUPS * HID;

    // fused prep: x16 + fragment-major Wbig + vtab
    const int PREP_TOTAL = PREP_X4 + PREP_WSWZ + PREP_V;
    prep_kernel<<<(PREP_TOTAL + 255) / 256, 256, 0, stream>>>(
        x, x16, W[0], W[1], W[2], Wf[0], Wf[1], Wf[2],
        As_[0], Ad[0], As_[1], Ad[1], As_[2], Ad[2], vtab[0], vtab[1], vtab[2]);

    // CSR by dst (with self loops)
    const int NB = (N_NODES + 255) / 256;   // 157
    hipMemsetAsync(deg, 0, (size_t)N_NODES * 4, stream);
    deg_count_kernel<<<(N_EDGES + 255) / 256, 256, 0, stream>>>(ei, deg);
    scan1_kernel<<<NB, 256, 0, stream>>>(deg, offsets, partial);
    scan2_kernel<<<1, 256, 0, stream>>>(partial, NB);
    scan3_kernel<<<NB, 256, 0, stream>>>(offsets, pos, partial);
    scatter_kernel<<<(N_EDGES + N_NODES + 255) / 256, 256, 0, stream>>>(ei, pos, csr);

    // layer-0 scores from x16 -> A
    scores3_kernel<64><<<NB, 256, 0, stream>>>(x16, vtab[0], ssrcA, sdstA);

    // layer 0: in x16 + scores A -> out h16A, scores B
    fused_layer_kernel<64, true><<<N_NODES / 16, 256, 0, stream>>>(
        x16, ssrcA, sdstA, offsets, csr, Wf[0], Bb[0], Gg[0], Be[0],
        vtab[1], h16A, ssrcB, sdstB);
    // layer 1: in h16A + scores B -> out h16B, scores A
    fused_layer_kernel<128, true><<<N_NODES / 16, 256, 0, stream>>>(
        h16A, ssrcB, sdstB, offsets, csr, Wf[1], Bb[1], Gg[1], Be[1],
        vtab[2], h16B, ssrcA, sdstA);
    // layer 2: in h16B + scores A -> out h16A, no score write
    fused_layer_kernel<128, false><<<N_NODES / 16, 256, 0, stream>>>(
        h16B, ssrcA, sdstA, offsets, csr, Wf[2], Bb[2], Gg[2], Be[2],
        nullptr, h16A, nullptr, nullptr);

    // global mean pool + MLP head
    hipMemsetAsync(pooled, 0, (size_t)NGROUPS * HID * 4 + (size_t)NGROUPS * 4, stream);
    pool_kernel<<<(N_NODES + 255) / 256, 128, 0, stream>>>(h16A, batch, pooled, counts);
    head_kernel<<<NGROUPS, 128, 0, stream>>>(pooled, counts, fc1_w, fc1_b, fc2_w, fc2_b,
                                             (float*)d_out);
}